// Round 2
// baseline (612.302 us; speedup 1.0000x reference)
//
#include <hip/hip_runtime.h>

#define NN 100000   // N_SRC == N_DST
#define FD 64       // IN_SRC == IN_DST == OUT
#define NE 1250000  // E
#define TR 16       // rows per block in linear kernel

// ---------- linear: out[i,c] = bias[c] + sum_k x[i,k]*W[c,k] ----------
// 16 rows/block staged through LDS (one coalesced float4/thread = 4KB tile),
// lane = out column, W row per lane in VGPRs, 4 accumulator chains per row.
__global__ __launch_bounds__(256) void linear64_lds(
    const float* __restrict__ x, const float* __restrict__ W,
    const float* __restrict__ b, float* __restrict__ out)
{
    __shared__ float xs[TR * FD];  // 4 KB
    const int t = threadIdx.x, lane = t & 63, wid = t >> 6;

    float wreg[FD];
    #pragma unroll
    for (int k4 = 0; k4 < FD / 4; k4++) {
        const float4 wv = *(const float4*)(W + (size_t)lane * FD + k4 * 4);
        wreg[4*k4+0] = wv.x; wreg[4*k4+1] = wv.y;
        wreg[4*k4+2] = wv.z; wreg[4*k4+3] = wv.w;
    }
    const float bias = b ? b[lane] : 0.0f;

    const size_t rowbase = (size_t)blockIdx.x * TR;
    // stage 16 rows (1024 floats) with 256 coalesced float4 loads
    *(float4*)(xs + 4 * t) = *(const float4*)(x + rowbase * FD + 4 * t);
    __syncthreads();

    #pragma unroll
    for (int rr = 0; rr < 4; rr++) {
        const int r = wid * 4 + rr;             // wave handles rows wid*4..+3
        const float* xr = xs + r * FD;
        float a0 = 0.f, a1 = 0.f, a2 = 0.f, a3 = 0.f;
        #pragma unroll
        for (int k4 = 0; k4 < 16; k4 += 4) {    // 4 independent chains
            const float4 v0 = *(const float4*)(xr + 4*(k4+0));  // LDS broadcast
            const float4 v1 = *(const float4*)(xr + 4*(k4+1));
            const float4 v2 = *(const float4*)(xr + 4*(k4+2));
            const float4 v3 = *(const float4*)(xr + 4*(k4+3));
            a0 = fmaf(v0.x, wreg[4*(k4+0)+0], a0); a0 = fmaf(v0.y, wreg[4*(k4+0)+1], a0);
            a0 = fmaf(v0.z, wreg[4*(k4+0)+2], a0); a0 = fmaf(v0.w, wreg[4*(k4+0)+3], a0);
            a1 = fmaf(v1.x, wreg[4*(k4+1)+0], a1); a1 = fmaf(v1.y, wreg[4*(k4+1)+1], a1);
            a1 = fmaf(v1.z, wreg[4*(k4+1)+2], a1); a1 = fmaf(v1.w, wreg[4*(k4+1)+3], a1);
            a2 = fmaf(v2.x, wreg[4*(k4+2)+0], a2); a2 = fmaf(v2.y, wreg[4*(k4+2)+1], a2);
            a2 = fmaf(v2.z, wreg[4*(k4+2)+2], a2); a2 = fmaf(v2.w, wreg[4*(k4+2)+3], a2);
            a3 = fmaf(v3.x, wreg[4*(k4+3)+0], a3); a3 = fmaf(v3.y, wreg[4*(k4+3)+1], a3);
            a3 = fmaf(v3.z, wreg[4*(k4+3)+2], a3); a3 = fmaf(v3.w, wreg[4*(k4+3)+3], a3);
        }
        out[(rowbase + r) * FD + lane] = bias + ((a0 + a1) + (a2 + a3));
    }
}

// ---------- counting sort of edges by dst ----------
__global__ __launch_bounds__(256) void hist_kernel(
    const int* __restrict__ dst, int* __restrict__ counts)
{
    const int e = blockIdx.x * blockDim.x + threadIdx.x;
    if (e < NE) atomicAdd(&counts[dst[e]], 1);
}

// single block of 1024 threads: exclusive scan of counts -> offsets & cursor
__global__ __launch_bounds__(1024) void scan_counts(
    const int* __restrict__ counts, int* __restrict__ offsets,
    int* __restrict__ cursor)
{
    __shared__ int wsum[16];
    const int t = threadIdx.x, lane = t & 63, wid = t >> 6;
    const int CH = (NN + 1023) >> 10;               // 98
    const int base = t * CH;
    const int end  = min(base + CH, NN);

    int s = 0;
    for (int i = base; i < end; i++) s += counts[i];

    int v = s;                                       // wave inclusive scan
    #pragma unroll
    for (int off = 1; off < 64; off <<= 1) {
        int u = __shfl_up(v, off, 64);
        if (lane >= off) v += u;
    }
    if (lane == 63) wsum[wid] = v;
    __syncthreads();
    if (wid == 0) {
        int wv = (lane < 16) ? wsum[lane] : 0;
        #pragma unroll
        for (int off = 1; off < 16; off <<= 1) {
            int u = __shfl_up(wv, off, 64);
            if (lane >= off) wv += u;
        }
        if (lane < 16) wsum[lane] = wv;              // inclusive wave sums
    }
    __syncthreads();
    const int wave_prefix = (wid > 0) ? wsum[wid - 1] : 0;
    int run = wave_prefix + v - s;                   // exclusive prefix for t
    for (int i = base; i < end; i++) {
        offsets[i] = run; cursor[i] = run; run += counts[i];
    }
    if (t == 1023) offsets[NN] = wsum[15];           // == NE
}

__global__ __launch_bounds__(256) void place_kernel(
    const int* __restrict__ src, const int* __restrict__ dst,
    const float* __restrict__ ew, int* __restrict__ cursor,
    int* __restrict__ s_src, float* __restrict__ s_w)
{
    const int e = blockIdx.x * blockDim.x + threadIdx.x;
    if (e < NE) {
        const int p = atomicAdd(&cursor[dst[e]], 1);
        s_src[p] = src[e];
        s_w[p]   = ew[e];
    }
}

// ---------- gather: one wave per dst row, no atomics ----------
__global__ __launch_bounds__(256) void gather_rows(
    const float* __restrict__ h, const int* __restrict__ offsets,
    const int* __restrict__ s_src, const float* __restrict__ s_w,
    float* __restrict__ out)
{
    const int lane = threadIdx.x & 63;
    const int row  = (int)((blockIdx.x * blockDim.x + threadIdx.x) >> 6);
    if (row >= NN) return;
    int j = offsets[row];
    const int jend = offsets[row + 1];
    float acc = 0.f;
    for (; j + 4 <= jend; j += 4) {                  // 4 gathers in flight
        const int   s0 = s_src[j],   s1 = s_src[j+1];
        const int   s2 = s_src[j+2], s3 = s_src[j+3];
        const float w0 = s_w[j],   w1 = s_w[j+1];
        const float w2 = s_w[j+2], w3 = s_w[j+3];
        const float h0 = h[(size_t)s0 * FD + lane];
        const float h1 = h[(size_t)s1 * FD + lane];
        const float h2 = h[(size_t)s2 * FD + lane];
        const float h3 = h[(size_t)s3 * FD + lane];
        acc = fmaf(h0, w0, acc); acc = fmaf(h1, w1, acc);
        acc = fmaf(h2, w2, acc); acc = fmaf(h3, w3, acc);
    }
    for (; j < jend; j++)
        acc = fmaf(h[(size_t)s_src[j] * FD + lane], s_w[j], acc);
    out[(size_t)row * FD + lane] += acc;             // unique owner, no atomic
}

// ---------- fallback: atomic scatter (round-1 path) ----------
__global__ __launch_bounds__(256) void scatter_edges(
    const float* __restrict__ h, const int* __restrict__ eidx,
    const float* __restrict__ ew, float* __restrict__ out)
{
    const int lane  = threadIdx.x & 63;
    const int gwave = (int)((blockIdx.x * blockDim.x + threadIdx.x) >> 6);
    const int nwave = (int)((gridDim.x * blockDim.x) >> 6);
    const int* __restrict__ src = eidx;
    const int* __restrict__ dst = eidx + NE;
    for (int e = gwave; e < NE; e += nwave) {
        const float v = h[(size_t)src[e] * FD + lane] * ew[e];
        atomicAdd(out + (size_t)dst[e] * FD + lane, v);
    }
}

extern "C" void kernel_launch(void* const* d_in, const int* in_sizes, int n_in,
                              void* d_out, int out_size, void* d_ws, size_t ws_size,
                              hipStream_t stream)
{
    const float* x_src  = (const float*)d_in[0];
    const float* x_dst  = (const float*)d_in[1];
    const int*   eidx   = (const int*)  d_in[2];   // [2,E]: src row then dst row
    const float* ew     = (const float*)d_in[3];
    const float* W_nei  = (const float*)d_in[4];
    const float* W_self = (const float*)d_in[5];
    const float* b_self = (const float*)d_in[6];
    float* out = (float*)d_out;

    const int* src = eidx;
    const int* dst = eidx + NE;

    // workspace layout (16B aligned)
    char* ws = (char*)d_ws;
    size_t off = 0;
    auto alloc = [&](size_t bytes) { char* p = ws + off; off += (bytes + 15) & ~(size_t)15; return p; };
    float* h       = (float*)alloc((size_t)NN * FD * sizeof(float)); // 25.6 MB
    int*   counts  = (int*)  alloc((size_t)NN * sizeof(int));
    int*   offsets = (int*)  alloc(((size_t)NN + 1) * sizeof(int));
    int*   cursor  = (int*)  alloc((size_t)NN * sizeof(int));
    int*   s_src   = (int*)  alloc((size_t)NE * sizeof(int));
    float* s_w     = (float*)alloc((size_t)NE * sizeof(float));
    const size_t need_sort = off;
    const size_t need_h    = (size_t)NN * FD * sizeof(float);

    // self term (fully overwrites out)
    linear64_lds<<<NN / TR, 256, 0, stream>>>(x_dst, W_self, b_self, out);

    if (ws_size >= need_sort) {
        linear64_lds<<<NN / TR, 256, 0, stream>>>(x_src, W_nei, nullptr, h);
        hipMemsetAsync(counts, 0, (size_t)NN * sizeof(int), stream);
        hist_kernel <<<(NE + 255) / 256, 256, 0, stream>>>(dst, counts);
        scan_counts <<<1, 1024, 0, stream>>>(counts, offsets, cursor);
        place_kernel<<<(NE + 255) / 256, 256, 0, stream>>>(src, dst, ew, cursor, s_src, s_w);
        gather_rows <<<(NN * 64 + 255) / 256, 256, 0, stream>>>(h, offsets, s_src, s_w, out);
    } else if (ws_size >= need_h) {
        linear64_lds<<<NN / TR, 256, 0, stream>>>(x_src, W_nei, nullptr, h);
        scatter_edges<<<2048, 256, 0, stream>>>(h, eidx, ew, out);
    }
}

// Round 3
// 400.409 us; speedup vs baseline: 1.5292x; 1.5292x over previous
//
#include <hip/hip_runtime.h>

#define NN 100000   // N_SRC == N_DST
#define FD 64       // IN_SRC == IN_DST == OUT
#define NE 1250000  // E
#define TR 16       // rows per block in linear kernel
#define CHUNK 2048  // scan chunk per block
#define NB ((NN + CHUNK - 1) / CHUNK)   // 49 scan blocks

// ---------- linear: out[i,c] = bias[c] + sum_k x[i,k]*W[c,k] ----------
__global__ __launch_bounds__(256) void linear64_lds(
    const float* __restrict__ x, const float* __restrict__ W,
    const float* __restrict__ b, float* __restrict__ out)
{
    __shared__ float xs[TR * FD];  // 4 KB
    const int t = threadIdx.x, lane = t & 63, wid = t >> 6;

    float wreg[FD];
    #pragma unroll
    for (int k4 = 0; k4 < FD / 4; k4++) {
        const float4 wv = *(const float4*)(W + (size_t)lane * FD + k4 * 4);
        wreg[4*k4+0] = wv.x; wreg[4*k4+1] = wv.y;
        wreg[4*k4+2] = wv.z; wreg[4*k4+3] = wv.w;
    }
    const float bias = b ? b[lane] : 0.0f;

    const size_t rowbase = (size_t)blockIdx.x * TR;
    *(float4*)(xs + 4 * t) = *(const float4*)(x + rowbase * FD + 4 * t);
    __syncthreads();

    #pragma unroll
    for (int rr = 0; rr < 4; rr++) {
        const int r = wid * 4 + rr;
        const float* xr = xs + r * FD;
        float a0 = 0.f, a1 = 0.f, a2 = 0.f, a3 = 0.f;
        #pragma unroll
        for (int k4 = 0; k4 < 16; k4 += 4) {
            const float4 v0 = *(const float4*)(xr + 4*(k4+0));
            const float4 v1 = *(const float4*)(xr + 4*(k4+1));
            const float4 v2 = *(const float4*)(xr + 4*(k4+2));
            const float4 v3 = *(const float4*)(xr + 4*(k4+3));
            a0 = fmaf(v0.x, wreg[4*(k4+0)+0], a0); a0 = fmaf(v0.y, wreg[4*(k4+0)+1], a0);
            a0 = fmaf(v0.z, wreg[4*(k4+0)+2], a0); a0 = fmaf(v0.w, wreg[4*(k4+0)+3], a0);
            a1 = fmaf(v1.x, wreg[4*(k4+1)+0], a1); a1 = fmaf(v1.y, wreg[4*(k4+1)+1], a1);
            a1 = fmaf(v1.z, wreg[4*(k4+1)+2], a1); a1 = fmaf(v1.w, wreg[4*(k4+1)+3], a1);
            a2 = fmaf(v2.x, wreg[4*(k4+2)+0], a2); a2 = fmaf(v2.y, wreg[4*(k4+2)+1], a2);
            a2 = fmaf(v2.z, wreg[4*(k4+2)+2], a2); a2 = fmaf(v2.w, wreg[4*(k4+2)+3], a2);
            a3 = fmaf(v3.x, wreg[4*(k4+3)+0], a3); a3 = fmaf(v3.y, wreg[4*(k4+3)+1], a3);
            a3 = fmaf(v3.z, wreg[4*(k4+3)+2], a3); a3 = fmaf(v3.w, wreg[4*(k4+3)+3], a3);
        }
        out[(rowbase + r) * FD + lane] = bias + ((a0 + a1) + (a2 + a3));
    }
}

// ---------- counting sort of edges by dst ----------
__global__ __launch_bounds__(256) void hist_kernel(
    const int* __restrict__ dst, int* __restrict__ counts)
{
    const int e = blockIdx.x * blockDim.x + threadIdx.x;
    if (e < NE) atomicAdd(&counts[dst[e]], 1);
}

// phase 1: each block reduces a 2048-elem chunk of counts -> bsum[b]
__global__ __launch_bounds__(256) void reduce_chunks(
    const int* __restrict__ counts, int* __restrict__ bsum)
{
    __shared__ int wsh[4];
    const int t = threadIdx.x, lane = t & 63, wid = t >> 6;
    const int base = blockIdx.x * CHUNK + t * 8;
    int s = 0;
    #pragma unroll
    for (int k = 0; k < 8; k++) {
        const int i = base + k;
        if (i < NN) s += counts[i];
    }
    #pragma unroll
    for (int off = 32; off > 0; off >>= 1) s += __shfl_xor(s, off, 64);
    if (lane == 0) wsh[wid] = s;
    __syncthreads();
    if (t == 0) bsum[blockIdx.x] = wsh[0] + wsh[1] + wsh[2] + wsh[3];
}

// phase 2: one wave scans the NB partials -> exclusive block bases
__global__ __launch_bounds__(64) void scan_partials(
    const int* __restrict__ bsum, int* __restrict__ bbase,
    int* __restrict__ offsets)
{
    const int lane = threadIdx.x;
    int v = (lane < NB) ? bsum[lane] : 0;
    int inc = v;
    #pragma unroll
    for (int off = 1; off < 64; off <<= 1) {
        int u = __shfl_up(inc, off, 64);
        if (lane >= off) inc += u;
    }
    if (lane < NB) bbase[lane] = inc - v;      // exclusive
    if (lane == 63) offsets[NN] = inc;         // total == NE
}

// phase 3: each block rescans its chunk, writes offsets & cursor
__global__ __launch_bounds__(256) void scan_chunks(
    const int* __restrict__ counts, const int* __restrict__ bbase,
    int* __restrict__ offsets, int* __restrict__ cursor)
{
    __shared__ int wsh[4];
    const int t = threadIdx.x, lane = t & 63, wid = t >> 6;
    const int base = blockIdx.x * CHUNK + t * 8;
    int v[8]; int s = 0;
    #pragma unroll
    for (int k = 0; k < 8; k++) {
        const int i = base + k;
        v[k] = (i < NN) ? counts[i] : 0;
        s += v[k];
    }
    int inc = s;
    #pragma unroll
    for (int off = 1; off < 64; off <<= 1) {
        int u = __shfl_up(inc, off, 64);
        if (lane >= off) inc += u;
    }
    if (lane == 63) wsh[wid] = inc;
    __syncthreads();
    int wprefix = 0;
    for (int w = 0; w < wid; w++) wprefix += wsh[w];
    int run = bbase[blockIdx.x] + wprefix + (inc - s);  // exclusive prefix
    #pragma unroll
    for (int k = 0; k < 8; k++) {
        const int i = base + k;
        if (i < NN) { offsets[i] = run; cursor[i] = run; }
        run += v[k];
    }
}

// place edges into dst-sorted order; (src, weight) packed as int2
__global__ __launch_bounds__(256) void place_kernel(
    const int* __restrict__ src, const int* __restrict__ dst,
    const float* __restrict__ ew, int* __restrict__ cursor,
    int2* __restrict__ sp)
{
    const int e = blockIdx.x * blockDim.x + threadIdx.x;
    if (e < NE) {
        const int p = atomicAdd(&cursor[dst[e]], 1);
        sp[p] = make_int2(src[e], __float_as_int(ew[e]));
    }
}

// ---------- gather: one wave per dst row, no atomics ----------
__global__ __launch_bounds__(256) void gather_rows(
    const float* __restrict__ h, const int* __restrict__ offsets,
    const int2* __restrict__ sp, float* __restrict__ out)
{
    const int lane = threadIdx.x & 63;
    const int row  = (int)((blockIdx.x * blockDim.x + threadIdx.x) >> 6);
    if (row >= NN) return;
    int j = offsets[row];
    const int jend = offsets[row + 1];
    float acc = 0.f;
    for (; j + 4 <= jend; j += 4) {
        const int2 p0 = sp[j],   p1 = sp[j+1];
        const int2 p2 = sp[j+2], p3 = sp[j+3];
        const float h0 = h[(size_t)p0.x * FD + lane];
        const float h1 = h[(size_t)p1.x * FD + lane];
        const float h2 = h[(size_t)p2.x * FD + lane];
        const float h3 = h[(size_t)p3.x * FD + lane];
        acc = fmaf(h0, __int_as_float(p0.y), acc);
        acc = fmaf(h1, __int_as_float(p1.y), acc);
        acc = fmaf(h2, __int_as_float(p2.y), acc);
        acc = fmaf(h3, __int_as_float(p3.y), acc);
    }
    for (; j < jend; j++) {
        const int2 p = sp[j];
        acc = fmaf(h[(size_t)p.x * FD + lane], __int_as_float(p.y), acc);
    }
    out[(size_t)row * FD + lane] += acc;
}

// ---------- fallback: atomic scatter ----------
__global__ __launch_bounds__(256) void scatter_edges(
    const float* __restrict__ h, const int* __restrict__ eidx,
    const float* __restrict__ ew, float* __restrict__ out)
{
    const int lane  = threadIdx.x & 63;
    const int gwave = (int)((blockIdx.x * blockDim.x + threadIdx.x) >> 6);
    const int nwave = (int)((gridDim.x * blockDim.x) >> 6);
    const int* __restrict__ src = eidx;
    const int* __restrict__ dst = eidx + NE;
    for (int e = gwave; e < NE; e += nwave) {
        const float v = h[(size_t)src[e] * FD + lane] * ew[e];
        atomicAdd(out + (size_t)dst[e] * FD + lane, v);
    }
}

extern "C" void kernel_launch(void* const* d_in, const int* in_sizes, int n_in,
                              void* d_out, int out_size, void* d_ws, size_t ws_size,
                              hipStream_t stream)
{
    const float* x_src  = (const float*)d_in[0];
    const float* x_dst  = (const float*)d_in[1];
    const int*   eidx   = (const int*)  d_in[2];   // [2,E]: src row then dst row
    const float* ew     = (const float*)d_in[3];
    const float* W_nei  = (const float*)d_in[4];
    const float* W_self = (const float*)d_in[5];
    const float* b_self = (const float*)d_in[6];
    float* out = (float*)d_out;

    const int* src = eidx;
    const int* dst = eidx + NE;

    // workspace layout (16B aligned)
    char* ws = (char*)d_ws;
    size_t off = 0;
    auto alloc = [&](size_t bytes) { char* p = ws + off; off += (bytes + 15) & ~(size_t)15; return p; };
    float* h       = (float*)alloc((size_t)NN * FD * sizeof(float)); // 25.6 MB
    int*   counts  = (int*)  alloc((size_t)NN * sizeof(int));
    int*   offsets = (int*)  alloc(((size_t)NN + 1) * sizeof(int));
    int*   cursor  = (int*)  alloc((size_t)NN * sizeof(int));
    int*   bsum    = (int*)  alloc((size_t)NB * sizeof(int));
    int*   bbase   = (int*)  alloc((size_t)NB * sizeof(int));
    int2*  sp      = (int2*) alloc((size_t)NE * sizeof(int2));       // 10 MB
    const size_t need_sort = off;
    const size_t need_h    = (size_t)NN * FD * sizeof(float);

    // self term (fully overwrites out)
    linear64_lds<<<NN / TR, 256, 0, stream>>>(x_dst, W_self, b_self, out);

    if (ws_size >= need_sort) {
        linear64_lds<<<NN / TR, 256, 0, stream>>>(x_src, W_nei, nullptr, h);
        hipMemsetAsync(counts, 0, (size_t)NN * sizeof(int), stream);
        hist_kernel   <<<(NE + 255) / 256, 256, 0, stream>>>(dst, counts);
        reduce_chunks <<<NB, 256, 0, stream>>>(counts, bsum);
        scan_partials <<<1, 64, 0, stream>>>(bsum, bbase, offsets);
        scan_chunks   <<<NB, 256, 0, stream>>>(counts, bbase, offsets, cursor);
        place_kernel  <<<(NE + 255) / 256, 256, 0, stream>>>(src, dst, ew, cursor, sp);
        gather_rows   <<<(NN * 64 + 255) / 256, 256, 0, stream>>>(h, offsets, sp, out);
    } else if (ws_size >= need_h) {
        linear64_lds<<<NN / TR, 256, 0, stream>>>(x_src, W_nei, nullptr, h);
        scatter_edges<<<2048, 256, 0, stream>>>(h, eidx, ew, out);
    }
}